// Round 11
// baseline (283.294 us; speedup 1.0000x reference)
//
#include <hip/hip_runtime.h>

#define NN 384
#define RR 8
#define NR (NN * RR)   // 3072

typedef _Float16 half2v __attribute__((ext_vector_type(2)));
typedef _Float16 half8v __attribute__((ext_vector_type(8)));

struct h2x4 { half2v v[4]; };
static __device__ inline h2x4 split4(half8v h) { return __builtin_bit_cast(h2x4, h); }

// ---------- prep: A (f32, 3072 chunks of 8) -> A2h (f16) in d_ws ----------
// A2 chunk q (q = a*NN+i) == A[8q..8q+8) because A[a*NR+i*8+b2] = A[(a*NN+i)*8+b2].
__global__ void prep_a2(const float* __restrict__ A, _Float16* __restrict__ A2h) {
    const int q = blockIdx.x * 256 + threadIdx.x;     // 0..3071
    if (q < NN * RR) {
        const float4 f0 = reinterpret_cast<const float4*>(A)[2 * q];
        const float4 f1 = reinterpret_cast<const float4*>(A)[2 * q + 1];
        half8v h;
        h[0] = (_Float16)f0.x; h[1] = (_Float16)f0.y; h[2] = (_Float16)f0.z; h[3] = (_Float16)f0.w;
        h[4] = (_Float16)f1.x; h[5] = (_Float16)f1.y; h[6] = (_Float16)f1.z; h[7] = (_Float16)f1.w;
        reinterpret_cast<half8v*>(A2h)[q] = h;
    }
}

// ---------- main: 256 thr / 32 pairs / block; LDS = 4KB Gh only ----------
// out[b,i] = sum_p A2[i,p]*G_b[p]; av chunks read from global A2h (L1/L2-hot),
// G broadcast from tiny LDS. Epilogue math identical to proven r10 path.
__global__ __launch_bounds__(256, 4)
void dtn_dot2e(const _Float16* __restrict__ A2h, const float* __restrict__ Bf,
               const float* __restrict__ C, const int* __restrict__ x,
               float* __restrict__ out)
{
    __shared__ __align__(16) _Float16 Gh[32 * 64];    // 4096 B

    const int t = threadIdx.x;
    const long b0 = (long)blockIdx.x * 32;

    // ---- G: thread -> (pair bl = t>>3, column a = t&7); computes G[b2][a].
    {
        const int bl = t >> 3;
        const int a  = t & 7;
        const int j = x[2 * (b0 + bl)];
        const int k = x[2 * (b0 + bl) + 1];
        const float* Bj = Bf + (size_t)j * RR;           // Bf[b2,j,c] at Bj[b2*NR + c]
        const float* Ck = C + (size_t)k * RR + a;        // C[c,k,a]   at Ck[c*NR]
        float ck[8];
        #pragma unroll
        for (int c = 0; c < 8; ++c)
            ck[c] = Ck[(size_t)c * NR];
        half8v h;
        #pragma unroll
        for (int b2 = 0; b2 < 8; ++b2) {
            const float4* br = reinterpret_cast<const float4*>(Bj + (size_t)b2 * NR);
            const float4 r0 = br[0];
            const float4 r1 = br[1];
            const float s = r0.x * ck[0] + r0.y * ck[1] + r0.z * ck[2] + r0.w * ck[3]
                          + r1.x * ck[4] + r1.y * ck[5] + r1.z * ck[6] + r1.w * ck[7];
            h[b2] = (_Float16)s;
        }
        *reinterpret_cast<half8v*>(&Gh[bl * 64 + a * 8]) = h;   // p = a*8 + b2
    }

    __syncthreads();

    // ---- Epilogue: wave wv owns pairs wv*8..+7; lane covers i = lane + 64*ii.
    const int lane = t & 63;
    const int wv = t >> 6;

    float acc[8][6];
    #pragma unroll
    for (int pp = 0; pp < 8; ++pp)
        #pragma unroll
        for (int ii = 0; ii < 6; ++ii)
            acc[pp][ii] = 0.f;

    #pragma unroll 1
    for (int c = 0; c < 8; ++c) {
        h2x4 av[6];
        #pragma unroll
        for (int ii = 0; ii < 6; ++ii)
            av[ii] = split4(*reinterpret_cast<const half8v*>(
                &A2h[(size_t)(c * NN + lane + 64 * ii) * 8]));
        #pragma unroll
        for (int pp = 0; pp < 8; ++pp) {
            const h2x4 g = split4(*reinterpret_cast<const half8v*>(
                &Gh[(wv * 8 + pp) * 64 + c * 8]));
            #pragma unroll
            for (int ii = 0; ii < 6; ++ii) {
                float s = acc[pp][ii];
                s = __builtin_amdgcn_fdot2(g.v[0], av[ii].v[0], s, false);
                s = __builtin_amdgcn_fdot2(g.v[1], av[ii].v[1], s, false);
                s = __builtin_amdgcn_fdot2(g.v[2], av[ii].v[2], s, false);
                s = __builtin_amdgcn_fdot2(g.v[3], av[ii].v[3], s, false);
                acc[pp][ii] = s;
            }
        }
    }

    float* obase = out + (size_t)(b0 + wv * 8) * NN + lane;
    #pragma unroll
    for (int pp = 0; pp < 8; ++pp) {
        #pragma unroll
        for (int ii = 0; ii < 6; ++ii)
            obase[(size_t)pp * NN + ii * 64] = acc[pp][ii];
    }
}

// ---------- fallback (r10 kernel, LDS-staged) if ws too small ----------
__global__ __launch_bounds__(512, 4)
void dtn_dot2d(const float* __restrict__ A, const float* __restrict__ Bf,
               const float* __restrict__ C, const int* __restrict__ x,
               float* __restrict__ out)
{
    __shared__ __align__(16) _Float16 A2c[8 * NN * 8];
    __shared__ __align__(16) _Float16 Gh[256 * 64];
    const int t = threadIdx.x;
    const long b0 = (long)blockIdx.x * 256;
    #pragma unroll
    for (int it = 0; it < 6; ++it) {
        const int idx = t + it * 512;
        const int i = idx >> 3;
        const int a = idx & 7;
        const float4* src = reinterpret_cast<const float4*>(A + (size_t)a * NR + (size_t)i * RR);
        const float4 f0 = src[0];
        const float4 f1 = src[1];
        half8v h;
        h[0] = (_Float16)f0.x; h[1] = (_Float16)f0.y; h[2] = (_Float16)f0.z; h[3] = (_Float16)f0.w;
        h[4] = (_Float16)f1.x; h[5] = (_Float16)f1.y; h[6] = (_Float16)f1.z; h[7] = (_Float16)f1.w;
        *reinterpret_cast<half8v*>(&A2c[(size_t)(a * NN + i) * 8]) = h;
    }
    #pragma unroll 1
    for (int bt = 0; bt < 4; ++bt) {
        const int bl = bt * 64 + (t >> 3);
        const int a  = t & 7;
        const int j = x[2 * (b0 + bl)];
        const int k = x[2 * (b0 + bl) + 1];
        const float* Bj = Bf + (size_t)j * RR;
        const float* Ck = C + (size_t)k * RR + a;
        float ck[8];
        #pragma unroll
        for (int c = 0; c < 8; ++c) ck[c] = Ck[(size_t)c * NR];
        half8v h;
        #pragma unroll
        for (int b2 = 0; b2 < 8; ++b2) {
            const float4* br = reinterpret_cast<const float4*>(Bj + (size_t)b2 * NR);
            const float4 r0 = br[0];
            const float4 r1 = br[1];
            const float s = r0.x * ck[0] + r0.y * ck[1] + r0.z * ck[2] + r0.w * ck[3]
                          + r1.x * ck[4] + r1.y * ck[5] + r1.z * ck[6] + r1.w * ck[7];
            h[b2] = (_Float16)s;
        }
        *reinterpret_cast<half8v*>(&Gh[bl * 64 + a * 8]) = h;
    }
    __syncthreads();
    const int lane = t & 63;
    const int wv = t >> 6;
    #pragma unroll 1
    for (int bt = 0; bt < 4; ++bt) {
        float acc[8][6];
        #pragma unroll
        for (int pp = 0; pp < 8; ++pp)
            #pragma unroll
            for (int ii = 0; ii < 6; ++ii) acc[pp][ii] = 0.f;
        #pragma unroll 1
        for (int c = 0; c < 8; ++c) {
            h2x4 av[6];
            #pragma unroll
            for (int ii = 0; ii < 6; ++ii)
                av[ii] = split4(*reinterpret_cast<const half8v*>(&A2c[(size_t)(c * NN + lane + 64 * ii) * 8]));
            #pragma unroll
            for (int pp = 0; pp < 8; ++pp) {
                const h2x4 g = split4(*reinterpret_cast<const half8v*>(&Gh[(bt * 64 + wv * 8 + pp) * 64 + c * 8]));
                #pragma unroll
                for (int ii = 0; ii < 6; ++ii) {
                    float s = acc[pp][ii];
                    s = __builtin_amdgcn_fdot2(g.v[0], av[ii].v[0], s, false);
                    s = __builtin_amdgcn_fdot2(g.v[1], av[ii].v[1], s, false);
                    s = __builtin_amdgcn_fdot2(g.v[2], av[ii].v[2], s, false);
                    s = __builtin_amdgcn_fdot2(g.v[3], av[ii].v[3], s, false);
                    acc[pp][ii] = s;
                }
            }
        }
        float* obase = out + (size_t)(b0 + bt * 64 + wv * 8) * NN + lane;
        #pragma unroll
        for (int pp = 0; pp < 8; ++pp)
            #pragma unroll
            for (int ii = 0; ii < 6; ++ii)
                obase[(size_t)pp * NN + ii * 64] = acc[pp][ii];
    }
}

extern "C" void kernel_launch(void* const* d_in, const int* in_sizes, int n_in,
                              void* d_out, int out_size, void* d_ws, size_t ws_size,
                              hipStream_t stream) {
    const float* A  = (const float*)d_in[0];
    const float* Bf = (const float*)d_in[1];
    const float* C  = (const float*)d_in[2];
    const int*   x  = (const int*)d_in[3];
    float* out = (float*)d_out;
    const int B = in_sizes[3] / 2;           // 524288
    if (ws_size >= (size_t)NN * RR * 8 * sizeof(_Float16)) {
        _Float16* A2h = (_Float16*)d_ws;
        prep_a2<<<12, 256, 0, stream>>>(A, A2h);
        dtn_dot2e<<<B / 32, 256, 0, stream>>>(A2h, Bf, C, x, out);
    } else {
        dtn_dot2d<<<B / 256, 512, 0, stream>>>(A, Bf, C, x, out);
    }
}